// Round 19
// baseline (279.105 us; speedup 1.0000x reference)
//
#include <hip/hip_runtime.h>

typedef float v4f __attribute__((ext_vector_type(4)));
typedef unsigned short u16;
typedef u16 u16x8 __attribute__((ext_vector_type(8)));
typedef unsigned u32x4 __attribute__((ext_vector_type(4)));

constexpr int PR  = 512;           // plane resolution
constexpr int CP  = 24;            // plane channels (OUT_DIM * RANK)
constexpr int FD  = 32;            // feature channels
constexpr int FR  = 128;           // feature resolution
constexpr int PSZ = PR * PR;
constexpr int NBUCK = 32768;       // 32^3 morton buckets
constexpr int FW  = 16;            // feature window size (voxels)
constexpr int FW0 = 56;            // window base: covers u in [56, 72)
constexpr int HW0 = 62;            // HOT window base (LDS-staged)
constexpr int HWN = 4;             // hot window voxels/axis: [62, 66)
constexpr int RSTRIDE = 33;        // LDS row stride (33 ≡ 1 mod 32: conflict-free)

__device__ inline u16 f2bf(float f) {            // RNE bf16
    unsigned u = __float_as_uint(f);
    return (u16)((u + 0x7fffu + ((u >> 16) & 1u)) >> 16);
}
__device__ inline float bf2f(u16 h) { return __uint_as_float((unsigned)h << 16); }

// ---------------------------------------------------------------------------
// Block swizzle: XCD-chunk (bijective) + CU-contiguity transpose.
// ---------------------------------------------------------------------------
__device__ inline int swizzle_wg(int bid, int nwg) {
    int q = nwg >> 3, r = nwg & 7;
    int xcd = bid & 7, j = bid >> 3;
    int chunk = (xcd < r) ? q + 1 : q;
    int cbase = (xcd < r) ? xcd * (q + 1) : r * (q + 1) + (xcd - r) * q;
    int c32 = chunk >> 5;
    int T = c32 << 5;
    int jj = (j < T) ? ((j & 31) * c32 + (j >> 5)) : j;
    return cbase + jj;
}

// ---------------------------------------------------------------------------
// Fused prologue (all parts independent):
//   [0,3072)    transpose planes f32 -> bf16 slabs [plane][group][512*512][8]
//   [3072,3136) pack central feature window bf16 wsF[voxel][32] (256 KB)
//   [3136,3168) zero the 128 KB histogram
// bucket_hist must NOT join this kernel (needs zeroed hist; no inter-block
// ordering exists within a launch).
// ---------------------------------------------------------------------------
__global__ __launch_bounds__(256) void prologue(
    const float* __restrict__ p0, const float* __restrict__ p1,
    const float* __restrict__ p2, u16* __restrict__ wsB,
    const float* __restrict__ feat, u16* __restrict__ wsF,
    unsigned* __restrict__ hist)
{
    int b = blockIdx.x;
    int t = threadIdx.x;
    if (b < 3072) {
        __shared__ float lds[CP][256];
        int p   = b >> 10;             // 1024 blocks per plane
        int rem = b & 1023;
        int y   = rem >> 1;
        int x0  = (rem & 1) << 8;
        const float* src = (p == 0) ? p0 : (p == 1) ? p1 : p2;
        #pragma unroll
        for (int c = 0; c < CP; ++c)
            lds[c][t] = src[c * PSZ + y * PR + x0 + t];   // coalesced
        __syncthreads();
        int tex = y * PR + x0 + t;
        #pragma unroll
        for (int g = 0; g < 3; ++g) {
            u16x8 w;
            #pragma unroll
            for (int k = 0; k < 8; ++k) w[k] = f2bf(lds[g * 8 + k][t]);
            *(u16x8*)(wsB + ((size_t)(p * 3 + g) * PSZ + tex) * 8) = w;
        }
    } else if (b < 3136) {
        int idx = (b - 3072) * 256 + t;          // 16384 = 16^3 * 4
        int og = idx & 3;
        int v  = idx >> 2;
        int x = v & 15, y = (v >> 4) & 15, z = v >> 8;
        size_t src = (size_t)(z + FW0) * FR * FR + (y + FW0) * FR + (x + FW0);
        u16x8 w;
        #pragma unroll
        for (int k = 0; k < 8; ++k)
            w[k] = f2bf(feat[(size_t)(og * 8 + k) * FR * FR * FR + src]);
        *(u16x8*)(wsF + (size_t)v * FD + og * 8) = w;
    } else {
        int k = (b - 3136) * 256 + t;            // 8192 x 16 B = 128 KB
        u32x4 z = {0u, 0u, 0u, 0u};
        *(u32x4*)(hist + k * 4) = z;
    }
}

// ---------------------------------------------------------------------------
// Morton bucketing
// ---------------------------------------------------------------------------
__device__ inline int cell5(float p) {
    int c = (int)floorf((p + 1.0f) * 16.0f);
    return min(max(c, 0), 31);
}
__device__ inline unsigned spread3(unsigned v) {
    return (v & 1u) | ((v & 2u) << 2) | ((v & 4u) << 4) | ((v & 8u) << 6) | ((v & 16u) << 8);
}
__device__ inline unsigned morton_key(float x, float y, float z) {
    return spread3((unsigned)cell5(x)) | (spread3((unsigned)cell5(y)) << 1)
         | (spread3((unsigned)cell5(z)) << 2);
}

__global__ __launch_bounds__(256) void bucket_hist(
    const float* __restrict__ pts, unsigned* __restrict__ hist, int n)
{
    int i = blockIdx.x * blockDim.x + threadIdx.x;
    if (i >= n) return;
    float x = pts[3 * i], y = pts[3 * i + 1], z = pts[3 * i + 2];
    atomicAdd(&hist[morton_key(x, y, z)], 1u);
}

// single-block exclusive scan: hist[32768] -> cursor[32768]
__global__ __launch_bounds__(1024) void scan_offsets(
    const unsigned* __restrict__ hist, unsigned* __restrict__ cursor)
{
    __shared__ unsigned sums[1024];
    int t = threadIdx.x;
    const int base = t * (NBUCK / 1024);
    unsigned loc[NBUCK / 1024];
    unsigned s = 0;
    #pragma unroll
    for (int j = 0; j < NBUCK / 1024; ++j) { loc[j] = s; s += hist[base + j]; }
    sums[t] = s;
    __syncthreads();
    for (int off = 1; off < 1024; off <<= 1) {
        unsigned v = (t >= off) ? sums[t - off] : 0u;
        __syncthreads();
        sums[t] += v;
        __syncthreads();
    }
    unsigned blockbase = (t == 0) ? 0u : sums[t - 1];
    #pragma unroll
    for (int j = 0; j < NBUCK / 1024; ++j) cursor[base + j] = blockbase + loc[j];
}

// scatter points into sorted order; original index rides in .w
__global__ __launch_bounds__(256) void scatter_pts(
    const float* __restrict__ pts, unsigned* __restrict__ cursor,
    v4f* __restrict__ sorted, int n)
{
    int i = blockIdx.x * blockDim.x + threadIdx.x;
    if (i >= n) return;
    float x = pts[3 * i], y = pts[3 * i + 1], z = pts[3 * i + 2];
    unsigned key = morton_key(x, y, z);
    unsigned pos = atomicAdd(&cursor[key], 1u);
    v4f v; v.x = x; v.y = y; v.z = z; v.w = __int_as_float(i);
    sorted[pos] = v;
}

// ---------------------------------------------------------------------------
// Plane bilinear for ONE channel group (8 ch = one out_dim), bf16 slabs,
// direct global gathers (L2-resident window per XCD octant: 3.1 MB).
// ---------------------------------------------------------------------------
template <int G>
__device__ inline float interp_group(const v4f pt, const u16* __restrict__ wsB)
{
    float cx[3] = {pt.x, pt.x, pt.y};
    float cy[3] = {pt.y, pt.z, pt.z};
    float pr[8] = {1.f, 1.f, 1.f, 1.f, 1.f, 1.f, 1.f, 1.f};
    #pragma unroll
    for (int p = 0; p < 3; ++p) {
        float ux = (cx[p] + 1.0f) * 0.5f * (float)(PR - 1);
        float uy = (cy[p] + 1.0f) * 0.5f * (float)(PR - 1);
        float lx = floorf(ux), ly = floorf(uy);
        float fx = ux - lx,   fy = uy - ly;
        int ix0 = (int)lx, iy0 = (int)ly;
        int ix1 = min(ix0 + 1, PR - 1);
        int iy1 = min(iy0 + 1, PR - 1);
        float wx0 = 1.f - fx, wx1 = fx;
        float wy0 = 1.f - fy, wy1 = fy;
        float w00 = wx0 * wy0, w01 = wx1 * wy0;
        float w10 = wx0 * wy1, w11 = wx1 * wy1;

        const u16* slab = wsB + (size_t)(p * 3 + G) * PSZ * 8;
        const u16x8 A = *(const u16x8*)(slab + (iy0 * PR + ix0) * 8);
        const u16x8 B = *(const u16x8*)(slab + (iy0 * PR + ix1) * 8);
        const u16x8 C = *(const u16x8*)(slab + (iy1 * PR + ix0) * 8);
        const u16x8 D = *(const u16x8*)(slab + (iy1 * PR + ix1) * 8);
        #pragma unroll
        for (int e = 0; e < 8; ++e) {
            float s = w00 * bf2f(A[e]) + w01 * bf2f(B[e])
                    + w10 * bf2f(C[e]) + w11 * bf2f(D[e]);
            pr[e] *= s;
        }
    }
    return ((pr[0] + pr[1]) + (pr[2] + pr[3]))
         + ((pr[4] + pr[5]) + (pr[6] + pr[7]));
}

template <int G>
__global__ __launch_bounds__(256, 8) void lrh_interp_g(
    const v4f* __restrict__ sorted, const u16* __restrict__ wsB,
    float* __restrict__ itp, int n)
{
    int wg = swizzle_wg(blockIdx.x, gridDim.x);
    int i = wg * 256 + threadIdx.x;
    if (i >= n) return;
    v4f pt = __builtin_nontemporal_load(&sorted[i]);
    float v = interp_group<G>(pt, wsB);
    __builtin_nontemporal_store(v, &itp[i]);      // wave: 1024 B contiguous
}

// ---------------------------------------------------------------------------
// Fused pass 3: group-2 bilinear + merge itp0/itp1 + trilinear feature
// lookup. Feature reads come from a 4 KB LDS copy of the HOT voxel window
// [62,66)^3; tiers: hot-LDS -> wsF-global -> exact f32 fallback. Rows
// staged in LDS [256][33] then stored cooperatively 8-lanes-per-row.
// ---------------------------------------------------------------------------
__global__ __launch_bounds__(256, 4) void lrh_g2_feat(
    const v4f* __restrict__ sorted, const u16* __restrict__ wsB,
    const float* __restrict__ itp0, const float* __restrict__ itp1,
    const u16* __restrict__ wsF, const float* __restrict__ feat,
    float* __restrict__ out, int n)
{
    __shared__ float rows[256][RSTRIDE];   // 33,792 B
    __shared__ unsigned sord[256];         //  1,024 B
    __shared__ u16 hwin[HWN * HWN * HWN * FD]; // 4,096 B  (total 38.9 KB -> 4 blk/CU)

    int wg = swizzle_wg(blockIdx.x, gridDim.x);
    int base = wg * 256;
    int t = threadIdx.x;
    int i = base + t;

    // stage hot window: thread t -> voxel v = t>>2, og = t&3
    {
        int v = t >> 2, og = t & 3;
        int hx = v & 3, hy = (v >> 2) & 3, hz = v >> 4;
        int wv = ((hz + HW0 - FW0) * FW + (hy + HW0 - FW0)) * FW + (hx + HW0 - FW0);
        u16x8 w = *(const u16x8*)(wsF + (size_t)wv * FD + og * 8);
        *(u16x8*)(hwin + v * FD + og * 8) = w;
    }
    __syncthreads();

    if (i < n) {
        v4f pt = __builtin_nontemporal_load(&sorted[i]);
        sord[t] = (unsigned)__float_as_int(pt.w);
        float v2 = interp_group<2>(pt, wsB);
        float ip[3];
        ip[0] = __builtin_nontemporal_load(&itp0[i]);
        ip[1] = __builtin_nontemporal_load(&itp1[i]);
        ip[2] = v2;

        float fr[3];
        int   j0[3];
        bool hot = true, inw = true;
        #pragma unroll
        for (int k = 0; k < 3; ++k) {
            float uu = (ip[k] + 1.0f) * 0.5f * (float)(FR - 1);
            float lf = floorf(uu);
            fr[k] = uu - lf;
            j0[k] = (int)lf;
            hot = hot && (j0[k] >= HW0) && (j0[k] <= HW0 + HWN - 2);
            inw = inw && (j0[k] >= FW0) && (j0[k] + 1 <= FW0 + FW - 1);
        }

        float wx1 = fr[0], wx0 = 1.f - fr[0];
        float wy1 = fr[1], wy0 = 1.f - fr[1];
        float wz1 = fr[2], wz0 = 1.f - fr[2];
        float wcn[8];
        #pragma unroll
        for (int m = 0; m < 8; ++m) {
            int bx = m & 1, by = (m >> 1) & 1, bz = m >> 2;
            wcn[m] = (bx ? wx1 : wx0) * (by ? wy1 : wy0) * (bz ? wz1 : wz0);
        }

        if (__builtin_expect(hot, 1)) {
            // LDS path: bit-identical to wsF (hwin is a verbatim copy)
            int lx = j0[0] - HW0, ly = j0[1] - HW0, lz = j0[2] - HW0;
            const u16* cp = hwin + (size_t)(((lz * HWN + ly) * HWN + lx) * FD);
            int ofs[8];
            #pragma unroll
            for (int m = 0; m < 8; ++m) {
                int bx = m & 1, by = (m >> 1) & 1, bz = m >> 2;
                ofs[m] = ((bz * HWN + by) * HWN + bx) * FD;
            }
            #pragma unroll
            for (int og = 0; og < 4; ++og) {
                float acc[8] = {0.f, 0.f, 0.f, 0.f, 0.f, 0.f, 0.f, 0.f};
                #pragma unroll
                for (int m = 0; m < 8; ++m) {
                    u16x8 f = *(const u16x8*)(cp + ofs[m] + og * 8);
                    #pragma unroll
                    for (int e = 0; e < 8; ++e)
                        acc[e] = fmaf(wcn[m], bf2f(f[e]), acc[e]);
                }
                v4f lo = {acc[0], acc[1], acc[2], acc[3]};
                v4f hi = {acc[4], acc[5], acc[6], acc[7]};
                *(v4f*)&rows[t][og * 8]     = lo;
                *(v4f*)&rows[t][og * 8 + 4] = hi;
            }
        } else if (inw) {
            int lx = j0[0] - FW0, ly = j0[1] - FW0, lz = j0[2] - FW0;
            const u16* cp = wsF + (size_t)(((lz * FW + ly) * FW + lx) * FD);
            int ofs[8];
            #pragma unroll
            for (int m = 0; m < 8; ++m) {
                int bx = m & 1, by = (m >> 1) & 1, bz = m >> 2;
                ofs[m] = ((bz * FW + by) * FW + bx) * FD;
            }
            #pragma unroll
            for (int og = 0; og < 4; ++og) {
                float acc[8] = {0.f, 0.f, 0.f, 0.f, 0.f, 0.f, 0.f, 0.f};
                #pragma unroll
                for (int m = 0; m < 8; ++m) {
                    u16x8 f = *(const u16x8*)(cp + ofs[m] + og * 8);
                    #pragma unroll
                    for (int e = 0; e < 8; ++e)
                        acc[e] = fmaf(wcn[m], bf2f(f[e]), acc[e]);
                }
                v4f lo = {acc[0], acc[1], acc[2], acc[3]};
                v4f hi = {acc[4], acc[5], acc[6], acc[7]};
                *(v4f*)&rows[t][og * 8]     = lo;
                *(v4f*)&rows[t][og * 8 + 4] = hi;
            }
        } else {
            // exact fallback: masked gather from the original f32 volume (rare)
            float v0[3], v1[3];
            int i0c[3], i1c[3];
            #pragma unroll
            for (int k = 0; k < 3; ++k) {
                int jj = j0[k];
                v0[k] = (jj   >= 0 && jj   < FR) ? 1.f : 0.f;
                v1[k] = (jj+1 >= 0 && jj+1 < FR) ? 1.f : 0.f;
                i0c[k] = min(max(jj,     0), FR - 1);
                i1c[k] = min(max(jj + 1, 0), FR - 1);
            }
            #pragma unroll
            for (int cg = 0; cg < 8; ++cg) {
                v4f acc = {0.f, 0.f, 0.f, 0.f};
                #pragma unroll
                for (int m = 0; m < 8; ++m) {
                    int bx = m & 1, by = (m >> 1) & 1, bz = m >> 2;
                    int xi = bx ? i1c[0] : i0c[0];
                    int yi = by ? i1c[1] : i0c[1];
                    int zi = bz ? i1c[2] : i0c[2];
                    float w = (bx ? fr[0] * v1[0] : (1.f - fr[0]) * v0[0])
                            * (by ? fr[1] * v1[1] : (1.f - fr[1]) * v0[1])
                            * (bz ? fr[2] * v1[2] : (1.f - fr[2]) * v0[2]);
                    int offc = zi * FR * FR + yi * FR + xi;
                    #pragma unroll
                    for (int c = 0; c < 4; ++c) {
                        const float* Fc = feat + (size_t)(cg * 4 + c) * (FR * FR * FR);
                        acc[c] = fmaf(w, Fc[offc], acc[c]);
                    }
                }
                *(v4f*)&rows[t][cg * 4] = acc;
            }
        }
    }
    __syncthreads();

    // cooperative scatter: 8 lanes per row -> each store instr = 8 full rows
    int e = t & 7;
    #pragma unroll
    for (int rb = 0; rb < 256; rb += 32) {
        int rr = rb + (t >> 3);
        if (base + rr < n) {
            unsigned orow = sord[rr];
            const float* lp = &rows[rr][e * 4];
            v4f v = {lp[0], lp[1], lp[2], lp[3]};
            *(v4f*)(out + (size_t)orow * FD + e * 4) = v;
        }
    }
}

extern "C" void kernel_launch(void* const* d_in, const int* in_sizes, int n_in,
                              void* d_out, int out_size, void* d_ws, size_t ws_size,
                              hipStream_t stream) {
    const float* pts  = (const float*)d_in[0];
    const float* p0   = (const float*)d_in[1];
    const float* p1   = (const float*)d_in[2];
    const float* p2   = (const float*)d_in[3];
    const float* feat = (const float*)d_in[4];
    float* out = (float*)d_out;
    int n = in_sizes[0] / 3;

    size_t off = 0;
    auto alloc = [&](size_t sz) { size_t o = off; off = (off + sz + 255) & ~(size_t)255; return o; };
    const size_t off_trans  = alloc((size_t)3 * PSZ * CP * sizeof(u16)); // 37.7 MB
    const size_t off_sorted = alloc((size_t)n * sizeof(v4f));            // 16 MB
    const size_t off_hist   = alloc(NBUCK * sizeof(unsigned));
    const size_t off_cursor = alloc(NBUCK * sizeof(unsigned));
    const size_t off_itp0   = alloc((size_t)n * sizeof(float));          // 4 MB
    const size_t off_itp1   = alloc((size_t)n * sizeof(float));          // 4 MB
    const size_t off_featw  = alloc((size_t)FW * FW * FW * FD * sizeof(u16)); // 256 KB

    char* ws = (char*)d_ws;
    u16*      wsB     = (u16*)(ws + off_trans);
    v4f*      sorted  = (v4f*)(ws + off_sorted);
    unsigned* hist    = (unsigned*)(ws + off_hist);
    unsigned* cursor  = (unsigned*)(ws + off_cursor);
    float*    itp0    = (float*)(ws + off_itp0);
    float*    itp1    = (float*)(ws + off_itp1);
    u16*      wsF     = (u16*)(ws + off_featw);

    int blocks = (n + 255) / 256;

    prologue<<<3168, 256, 0, stream>>>(p0, p1, p2, wsB, feat, wsF, hist);
    bucket_hist<<<blocks, 256, 0, stream>>>(pts, hist, n);
    scan_offsets<<<1, 1024, 0, stream>>>(hist, cursor);
    scatter_pts<<<blocks, 256, 0, stream>>>(pts, cursor, sorted, n);
    lrh_interp_g<0><<<blocks, 256, 0, stream>>>(sorted, wsB, itp0, n);
    lrh_interp_g<1><<<blocks, 256, 0, stream>>>(sorted, wsB, itp1, n);
    lrh_g2_feat<<<blocks, 256, 0, stream>>>(sorted, wsB, itp0, itp1, wsF, feat, out, n);
}

// Round 20
// 274.662 us; speedup vs baseline: 1.0162x; 1.0162x over previous
//
#include <hip/hip_runtime.h>

typedef float v4f __attribute__((ext_vector_type(4)));
typedef unsigned short u16;
typedef u16 u16x8 __attribute__((ext_vector_type(8)));
typedef unsigned u32x4 __attribute__((ext_vector_type(4)));

constexpr int PR  = 512;           // plane resolution
constexpr int CP  = 24;            // plane channels (OUT_DIM * RANK)
constexpr int FD  = 32;            // feature channels
constexpr int FR  = 128;           // feature resolution
constexpr int PSZ = PR * PR;
constexpr int NBUCK = 32768;       // 32^3 morton buckets
constexpr int FW  = 16;            // feature window size (voxels)
constexpr int FW0 = 56;            // window base: covers u in [56, 72)
constexpr int HW0 = 62;            // HOT window base (LDS-staged)
constexpr int HWN = 4;             // hot window voxels/axis: [62, 66)
constexpr int RSTRIDE = 33;        // LDS row stride (33 ≡ 1 mod 32: conflict-free)

__device__ inline u16 f2bf(float f) {            // RNE bf16
    unsigned u = __float_as_uint(f);
    return (u16)((u + 0x7fffu + ((u >> 16) & 1u)) >> 16);
}
__device__ inline float bf2f(u16 h) { return __uint_as_float((unsigned)h << 16); }

// ---------------------------------------------------------------------------
// Block swizzle: XCD-chunk (bijective) + CU-contiguity transpose.
// ---------------------------------------------------------------------------
__device__ inline int swizzle_wg(int bid, int nwg) {
    int q = nwg >> 3, r = nwg & 7;
    int xcd = bid & 7, j = bid >> 3;
    int chunk = (xcd < r) ? q + 1 : q;
    int cbase = (xcd < r) ? xcd * (q + 1) : r * (q + 1) + (xcd - r) * q;
    int c32 = chunk >> 5;
    int T = c32 << 5;
    int jj = (j < T) ? ((j & 31) * c32 + (j >> 5)) : j;
    return cbase + jj;
}

// ---------------------------------------------------------------------------
// Fused prologue (all parts independent):
//   [0,3072)    transpose planes f32 -> bf16 slabs [plane][group][512*512][8]
//   [3072,3136) pack central feature window bf16 wsF[voxel][32] (256 KB)
//   [3136,3168) zero the 128 KB histogram
// bucket_hist must NOT join this kernel (needs zeroed hist; no inter-block
// ordering exists within a launch).
// ---------------------------------------------------------------------------
__global__ __launch_bounds__(256) void prologue(
    const float* __restrict__ p0, const float* __restrict__ p1,
    const float* __restrict__ p2, u16* __restrict__ wsB,
    const float* __restrict__ feat, u16* __restrict__ wsF,
    unsigned* __restrict__ hist)
{
    int b = blockIdx.x;
    int t = threadIdx.x;
    if (b < 3072) {
        __shared__ float lds[CP][256];
        int p   = b >> 10;             // 1024 blocks per plane
        int rem = b & 1023;
        int y   = rem >> 1;
        int x0  = (rem & 1) << 8;
        const float* src = (p == 0) ? p0 : (p == 1) ? p1 : p2;
        #pragma unroll
        for (int c = 0; c < CP; ++c)
            lds[c][t] = src[c * PSZ + y * PR + x0 + t];   // coalesced
        __syncthreads();
        int tex = y * PR + x0 + t;
        #pragma unroll
        for (int g = 0; g < 3; ++g) {
            u16x8 w;
            #pragma unroll
            for (int k = 0; k < 8; ++k) w[k] = f2bf(lds[g * 8 + k][t]);
            *(u16x8*)(wsB + ((size_t)(p * 3 + g) * PSZ + tex) * 8) = w;
        }
    } else if (b < 3136) {
        int idx = (b - 3072) * 256 + t;          // 16384 = 16^3 * 4
        int og = idx & 3;
        int v  = idx >> 2;
        int x = v & 15, y = (v >> 4) & 15, z = v >> 8;
        size_t src = (size_t)(z + FW0) * FR * FR + (y + FW0) * FR + (x + FW0);
        u16x8 w;
        #pragma unroll
        for (int k = 0; k < 8; ++k)
            w[k] = f2bf(feat[(size_t)(og * 8 + k) * FR * FR * FR + src]);
        *(u16x8*)(wsF + (size_t)v * FD + og * 8) = w;
    } else {
        int k = (b - 3136) * 256 + t;            // 8192 x 16 B = 128 KB
        u32x4 z = {0u, 0u, 0u, 0u};
        *(u32x4*)(hist + k * 4) = z;
    }
}

// ---------------------------------------------------------------------------
// Morton bucketing
// ---------------------------------------------------------------------------
__device__ inline int cell5(float p) {
    int c = (int)floorf((p + 1.0f) * 16.0f);
    return min(max(c, 0), 31);
}
__device__ inline unsigned spread3(unsigned v) {
    return (v & 1u) | ((v & 2u) << 2) | ((v & 4u) << 4) | ((v & 8u) << 6) | ((v & 16u) << 8);
}
__device__ inline unsigned morton_key(float x, float y, float z) {
    return spread3((unsigned)cell5(x)) | (spread3((unsigned)cell5(y)) << 1)
         | (spread3((unsigned)cell5(z)) << 2);
}

__global__ __launch_bounds__(256) void bucket_hist(
    const float* __restrict__ pts, unsigned* __restrict__ hist, int n)
{
    int i = blockIdx.x * blockDim.x + threadIdx.x;
    if (i >= n) return;
    float x = pts[3 * i], y = pts[3 * i + 1], z = pts[3 * i + 2];
    atomicAdd(&hist[morton_key(x, y, z)], 1u);
}

// single-block exclusive scan: hist[32768] -> cursor[32768]
__global__ __launch_bounds__(1024) void scan_offsets(
    const unsigned* __restrict__ hist, unsigned* __restrict__ cursor)
{
    __shared__ unsigned sums[1024];
    int t = threadIdx.x;
    const int base = t * (NBUCK / 1024);
    unsigned loc[NBUCK / 1024];
    unsigned s = 0;
    #pragma unroll
    for (int j = 0; j < NBUCK / 1024; ++j) { loc[j] = s; s += hist[base + j]; }
    sums[t] = s;
    __syncthreads();
    for (int off = 1; off < 1024; off <<= 1) {
        unsigned v = (t >= off) ? sums[t - off] : 0u;
        __syncthreads();
        sums[t] += v;
        __syncthreads();
    }
    unsigned blockbase = (t == 0) ? 0u : sums[t - 1];
    #pragma unroll
    for (int j = 0; j < NBUCK / 1024; ++j) cursor[base + j] = blockbase + loc[j];
}

// scatter points into sorted order; original index rides in .w
__global__ __launch_bounds__(256) void scatter_pts(
    const float* __restrict__ pts, unsigned* __restrict__ cursor,
    v4f* __restrict__ sorted, int n)
{
    int i = blockIdx.x * blockDim.x + threadIdx.x;
    if (i >= n) return;
    float x = pts[3 * i], y = pts[3 * i + 1], z = pts[3 * i + 2];
    unsigned key = morton_key(x, y, z);
    unsigned pos = atomicAdd(&cursor[key], 1u);
    v4f v; v.x = x; v.y = y; v.z = z; v.w = __int_as_float(i);
    sorted[pos] = v;
}

// ---------------------------------------------------------------------------
// Plane bilinear for ONE channel group (8 ch = one out_dim), bf16 slabs,
// direct global gathers (L2-resident window per XCD octant: 3.1 MB).
// ---------------------------------------------------------------------------
template <int G>
__device__ inline float interp_group(const v4f pt, const u16* __restrict__ wsB)
{
    float cx[3] = {pt.x, pt.x, pt.y};
    float cy[3] = {pt.y, pt.z, pt.z};
    float pr[8] = {1.f, 1.f, 1.f, 1.f, 1.f, 1.f, 1.f, 1.f};
    #pragma unroll
    for (int p = 0; p < 3; ++p) {
        float ux = (cx[p] + 1.0f) * 0.5f * (float)(PR - 1);
        float uy = (cy[p] + 1.0f) * 0.5f * (float)(PR - 1);
        float lx = floorf(ux), ly = floorf(uy);
        float fx = ux - lx,   fy = uy - ly;
        int ix0 = (int)lx, iy0 = (int)ly;
        int ix1 = min(ix0 + 1, PR - 1);
        int iy1 = min(iy0 + 1, PR - 1);
        float wx0 = 1.f - fx, wx1 = fx;
        float wy0 = 1.f - fy, wy1 = fy;
        float w00 = wx0 * wy0, w01 = wx1 * wy0;
        float w10 = wx0 * wy1, w11 = wx1 * wy1;

        const u16* slab = wsB + (size_t)(p * 3 + G) * PSZ * 8;
        const u16x8 A = *(const u16x8*)(slab + (iy0 * PR + ix0) * 8);
        const u16x8 B = *(const u16x8*)(slab + (iy0 * PR + ix1) * 8);
        const u16x8 C = *(const u16x8*)(slab + (iy1 * PR + ix0) * 8);
        const u16x8 D = *(const u16x8*)(slab + (iy1 * PR + ix1) * 8);
        #pragma unroll
        for (int e = 0; e < 8; ++e) {
            float s = w00 * bf2f(A[e]) + w01 * bf2f(B[e])
                    + w10 * bf2f(C[e]) + w11 * bf2f(D[e]);
            pr[e] *= s;
        }
    }
    return ((pr[0] + pr[1]) + (pr[2] + pr[3]))
         + ((pr[4] + pr[5]) + (pr[6] + pr[7]));
}

template <int G>
__global__ __launch_bounds__(256, 8) void lrh_interp_g(
    const v4f* __restrict__ sorted, const u16* __restrict__ wsB,
    float* __restrict__ itp, int n)
{
    int wg = swizzle_wg(blockIdx.x, gridDim.x);
    int i = wg * 256 + threadIdx.x;
    if (i >= n) return;
    v4f pt = __builtin_nontemporal_load(&sorted[i]);
    float v = interp_group<G>(pt, wsB);
    __builtin_nontemporal_store(v, &itp[i]);      // wave: 1024 B contiguous
}

// ---------------------------------------------------------------------------
// Fused pass 3: group-2 bilinear + merge itp0/itp1 + trilinear feature
// lookup. Feature reads come from a 4 KB LDS copy of the HOT voxel window
// [62,66)^3; tiers: hot-LDS -> wsF-global -> exact f32 fallback. Rows
// staged in LDS [256][33] then stored cooperatively 8-lanes-per-row.
// ---------------------------------------------------------------------------
__global__ __launch_bounds__(256, 4) void lrh_g2_feat(
    const v4f* __restrict__ sorted, const u16* __restrict__ wsB,
    const float* __restrict__ itp0, const float* __restrict__ itp1,
    const u16* __restrict__ wsF, const float* __restrict__ feat,
    float* __restrict__ out, int n)
{
    __shared__ float rows[256][RSTRIDE];   // 33,792 B
    __shared__ unsigned sord[256];         //  1,024 B
    __shared__ u16 hwin[HWN * HWN * HWN * FD]; // 4,096 B  (total 38.9 KB -> 4 blk/CU)

    int wg = swizzle_wg(blockIdx.x, gridDim.x);
    int base = wg * 256;
    int t = threadIdx.x;
    int i = base + t;

    // stage hot window: thread t -> voxel v = t>>2, og = t&3
    {
        int v = t >> 2, og = t & 3;
        int hx = v & 3, hy = (v >> 2) & 3, hz = v >> 4;
        int wv = ((hz + HW0 - FW0) * FW + (hy + HW0 - FW0)) * FW + (hx + HW0 - FW0);
        u16x8 w = *(const u16x8*)(wsF + (size_t)wv * FD + og * 8);
        *(u16x8*)(hwin + v * FD + og * 8) = w;
    }
    __syncthreads();

    if (i < n) {
        v4f pt = __builtin_nontemporal_load(&sorted[i]);
        sord[t] = (unsigned)__float_as_int(pt.w);
        float v2 = interp_group<2>(pt, wsB);
        float ip[3];
        ip[0] = __builtin_nontemporal_load(&itp0[i]);
        ip[1] = __builtin_nontemporal_load(&itp1[i]);
        ip[2] = v2;

        float fr[3];
        int   j0[3];
        bool hot = true, inw = true;
        #pragma unroll
        for (int k = 0; k < 3; ++k) {
            float uu = (ip[k] + 1.0f) * 0.5f * (float)(FR - 1);
            float lf = floorf(uu);
            fr[k] = uu - lf;
            j0[k] = (int)lf;
            hot = hot && (j0[k] >= HW0) && (j0[k] <= HW0 + HWN - 2);
            inw = inw && (j0[k] >= FW0) && (j0[k] + 1 <= FW0 + FW - 1);
        }

        float wx1 = fr[0], wx0 = 1.f - fr[0];
        float wy1 = fr[1], wy0 = 1.f - fr[1];
        float wz1 = fr[2], wz0 = 1.f - fr[2];
        float wcn[8];
        #pragma unroll
        for (int m = 0; m < 8; ++m) {
            int bx = m & 1, by = (m >> 1) & 1, bz = m >> 2;
            wcn[m] = (bx ? wx1 : wx0) * (by ? wy1 : wy0) * (bz ? wz1 : wz0);
        }

        if (__builtin_expect(hot, 1)) {
            // LDS path: bit-identical to wsF (hwin is a verbatim copy)
            int lx = j0[0] - HW0, ly = j0[1] - HW0, lz = j0[2] - HW0;
            const u16* cp = hwin + (size_t)(((lz * HWN + ly) * HWN + lx) * FD);
            int ofs[8];
            #pragma unroll
            for (int m = 0; m < 8; ++m) {
                int bx = m & 1, by = (m >> 1) & 1, bz = m >> 2;
                ofs[m] = ((bz * HWN + by) * HWN + bx) * FD;
            }
            #pragma unroll
            for (int og = 0; og < 4; ++og) {
                float acc[8] = {0.f, 0.f, 0.f, 0.f, 0.f, 0.f, 0.f, 0.f};
                #pragma unroll
                for (int m = 0; m < 8; ++m) {
                    u16x8 f = *(const u16x8*)(cp + ofs[m] + og * 8);
                    #pragma unroll
                    for (int e = 0; e < 8; ++e)
                        acc[e] = fmaf(wcn[m], bf2f(f[e]), acc[e]);
                }
                v4f lo = {acc[0], acc[1], acc[2], acc[3]};
                v4f hi = {acc[4], acc[5], acc[6], acc[7]};
                *(v4f*)&rows[t][og * 8]     = lo;
                *(v4f*)&rows[t][og * 8 + 4] = hi;
            }
        } else if (inw) {
            int lx = j0[0] - FW0, ly = j0[1] - FW0, lz = j0[2] - FW0;
            const u16* cp = wsF + (size_t)(((lz * FW + ly) * FW + lx) * FD);
            int ofs[8];
            #pragma unroll
            for (int m = 0; m < 8; ++m) {
                int bx = m & 1, by = (m >> 1) & 1, bz = m >> 2;
                ofs[m] = ((bz * FW + by) * FW + bx) * FD;
            }
            #pragma unroll
            for (int og = 0; og < 4; ++og) {
                float acc[8] = {0.f, 0.f, 0.f, 0.f, 0.f, 0.f, 0.f, 0.f};
                #pragma unroll
                for (int m = 0; m < 8; ++m) {
                    u16x8 f = *(const u16x8*)(cp + ofs[m] + og * 8);
                    #pragma unroll
                    for (int e = 0; e < 8; ++e)
                        acc[e] = fmaf(wcn[m], bf2f(f[e]), acc[e]);
                }
                v4f lo = {acc[0], acc[1], acc[2], acc[3]};
                v4f hi = {acc[4], acc[5], acc[6], acc[7]};
                *(v4f*)&rows[t][og * 8]     = lo;
                *(v4f*)&rows[t][og * 8 + 4] = hi;
            }
        } else {
            // exact fallback: masked gather from the original f32 volume (rare)
            float v0[3], v1[3];
            int i0c[3], i1c[3];
            #pragma unroll
            for (int k = 0; k < 3; ++k) {
                int jj = j0[k];
                v0[k] = (jj   >= 0 && jj   < FR) ? 1.f : 0.f;
                v1[k] = (jj+1 >= 0 && jj+1 < FR) ? 1.f : 0.f;
                i0c[k] = min(max(jj,     0), FR - 1);
                i1c[k] = min(max(jj + 1, 0), FR - 1);
            }
            #pragma unroll
            for (int cg = 0; cg < 8; ++cg) {
                v4f acc = {0.f, 0.f, 0.f, 0.f};
                #pragma unroll
                for (int m = 0; m < 8; ++m) {
                    int bx = m & 1, by = (m >> 1) & 1, bz = m >> 2;
                    int xi = bx ? i1c[0] : i0c[0];
                    int yi = by ? i1c[1] : i0c[1];
                    int zi = bz ? i1c[2] : i0c[2];
                    float w = (bx ? fr[0] * v1[0] : (1.f - fr[0]) * v0[0])
                            * (by ? fr[1] * v1[1] : (1.f - fr[1]) * v0[1])
                            * (bz ? fr[2] * v1[2] : (1.f - fr[2]) * v0[2]);
                    int offc = zi * FR * FR + yi * FR + xi;
                    #pragma unroll
                    for (int c = 0; c < 4; ++c) {
                        const float* Fc = feat + (size_t)(cg * 4 + c) * (FR * FR * FR);
                        acc[c] = fmaf(w, Fc[offc], acc[c]);
                    }
                }
                *(v4f*)&rows[t][cg * 4] = acc;
            }
        }
    }
    __syncthreads();

    // cooperative scatter: 8 lanes per row -> each store instr = 8 full rows
    int e = t & 7;
    #pragma unroll
    for (int rb = 0; rb < 256; rb += 32) {
        int rr = rb + (t >> 3);
        if (base + rr < n) {
            unsigned orow = sord[rr];
            const float* lp = &rows[rr][e * 4];
            v4f v = {lp[0], lp[1], lp[2], lp[3]};
            *(v4f*)(out + (size_t)orow * FD + e * 4) = v;
        }
    }
}

extern "C" void kernel_launch(void* const* d_in, const int* in_sizes, int n_in,
                              void* d_out, int out_size, void* d_ws, size_t ws_size,
                              hipStream_t stream) {
    const float* pts  = (const float*)d_in[0];
    const float* p0   = (const float*)d_in[1];
    const float* p1   = (const float*)d_in[2];
    const float* p2   = (const float*)d_in[3];
    const float* feat = (const float*)d_in[4];
    float* out = (float*)d_out;
    int n = in_sizes[0] / 3;

    size_t off = 0;
    auto alloc = [&](size_t sz) { size_t o = off; off = (off + sz + 255) & ~(size_t)255; return o; };
    const size_t off_trans  = alloc((size_t)3 * PSZ * CP * sizeof(u16)); // 37.7 MB
    const size_t off_sorted = alloc((size_t)n * sizeof(v4f));            // 16 MB
    const size_t off_hist   = alloc(NBUCK * sizeof(unsigned));
    const size_t off_cursor = alloc(NBUCK * sizeof(unsigned));
    const size_t off_itp0   = alloc((size_t)n * sizeof(float));          // 4 MB
    const size_t off_itp1   = alloc((size_t)n * sizeof(float));          // 4 MB
    const size_t off_featw  = alloc((size_t)FW * FW * FW * FD * sizeof(u16)); // 256 KB

    char* ws = (char*)d_ws;
    u16*      wsB     = (u16*)(ws + off_trans);
    v4f*      sorted  = (v4f*)(ws + off_sorted);
    unsigned* hist    = (unsigned*)(ws + off_hist);
    unsigned* cursor  = (unsigned*)(ws + off_cursor);
    float*    itp0    = (float*)(ws + off_itp0);
    float*    itp1    = (float*)(ws + off_itp1);
    u16*      wsF     = (u16*)(ws + off_featw);

    int blocks = (n + 255) / 256;

    prologue<<<3168, 256, 0, stream>>>(p0, p1, p2, wsB, feat, wsF, hist);
    bucket_hist<<<blocks, 256, 0, stream>>>(pts, hist, n);
    scan_offsets<<<1, 1024, 0, stream>>>(hist, cursor);
    scatter_pts<<<blocks, 256, 0, stream>>>(pts, cursor, sorted, n);
    lrh_interp_g<0><<<blocks, 256, 0, stream>>>(sorted, wsB, itp0, n);
    lrh_interp_g<1><<<blocks, 256, 0, stream>>>(sorted, wsB, itp1, n);
    lrh_g2_feat<<<blocks, 256, 0, stream>>>(sorted, wsB, itp0, itp1, wsF, feat, out, n);
}